// Round 7
// baseline (434.815 us; speedup 1.0000x reference)
//
#include <hip/hip_runtime.h>
#include <hip/hip_bf16.h>

// Problem constants
#define BB 64     // batch
#define NT 128    // text tokens
#define NV 256    // visual tokens
#define DD 512    // feature dim (bytes per row in fp8)
#define BKB 128   // K-chunk bytes: two 32x32x64 f8f6f4 k-steps
#define EPSF 1e-7f

typedef __attribute__((ext_vector_type(8))) int i32x8;
typedef __attribute__((ext_vector_type(4))) int i32x4;
typedef __attribute__((ext_vector_type(16))) float f32x16;

__device__ __forceinline__ void glds16(const uchar* g, uchar* l) {
    __builtin_amdgcn_global_load_lds(
        (const __attribute__((address_space(1))) unsigned int*)g,
        (__attribute__((address_space(3))) unsigned int*)l, 16, 0, 0);
}

// ---------------------------------------------------------------------------
// Kernel 1: L2-normalize rows, write fp8 e4m3 (OCP). Wave per row; 4 rows
// per 256-thread block. Block 0 zeroes reg_sum.
// ---------------------------------------------------------------------------
__global__ __launch_bounds__(256) void k_normalize(
    const float* __restrict__ tf, const float* __restrict__ vf,
    uchar* __restrict__ tn, uchar* __restrict__ vn,
    float* __restrict__ reg_sum) {
    if (blockIdx.x == 0 && threadIdx.x == 0) *reg_sum = 0.0f;
    const int w = threadIdx.x >> 6, l = threadIdx.x & 63;
    const int row = blockIdx.x * 4 + w;
    const float* src;
    uchar* dst;
    if (row < BB * NT) {
        src = tf + (size_t)row * DD;
        dst = tn + (size_t)row * DD;
    } else {
        int r = row - BB * NT;
        src = vf + (size_t)r * DD;
        dst = vn + (size_t)r * DD;
    }
    float4 x0 = ((const float4*)src)[l * 2];
    float4 x1 = ((const float4*)src)[l * 2 + 1];
    float ss = x0.x * x0.x + x0.y * x0.y + x0.z * x0.z + x0.w * x0.w
             + x1.x * x1.x + x1.y * x1.y + x1.z * x1.z + x1.w * x1.w;
    #pragma unroll
    for (int off = 32; off; off >>= 1) ss += __shfl_xor(ss, off, 64);
    float scale = 1.0f / fmaxf(sqrtf(ss), 1e-12f);
    int p0 = __builtin_amdgcn_cvt_pk_fp8_f32(x0.x * scale, x0.y * scale, 0, 0);
    p0 = __builtin_amdgcn_cvt_pk_fp8_f32(x0.z * scale, x0.w * scale, p0, 1);
    int p1 = __builtin_amdgcn_cvt_pk_fp8_f32(x1.x * scale, x1.y * scale, 0, 0);
    p1 = __builtin_amdgcn_cvt_pk_fp8_f32(x1.z * scale, x1.w * scale, p1, 1);
    ((uint2*)dst)[l] = make_uint2((unsigned)p0, (unsigned)p1);
}

// ---------------------------------------------------------------------------
// Kernel 2 (MX-fp8, 32x32x64): grid (i=64, jj=128); block handles all 128
// text tokens of batch i vs visual tokens [jj*128, jj*128+128) (half of
// batch j = jj>>1). 256 threads = 4 waves (2x2); wave tile 64x64 via 2x2
// tiles of mfma_scale_f32_32x32x64_f8f6f4 (fp8 e4m3, scales=1.0).
// R6 lesson: __launch_bounds__ min-waves arg CAPS the unified reg file;
// (256,3) capped below the ~150-reg liveness -> 96 KB/block accumulator
// spill -> 1.3 GB HBM traffic. Plain (256) lets the allocator fit
// liveness (no scratch); ~170 regs still gives ~3 blocks/CU.
// LDS rows 128 B = 8 16B-granules, rotation swizzle p=(g+row)&7 on the
// DMA global side + frag reads (R3/R5/R6-validated, absmax 0.0).
// A-frag layout 32x32x64: lane: row = l&31, k = (l>>5)*32 + byte.
// C/D layout 32x32: col = l&31, row = (reg&3) + 8*(reg>>2) + 4*(l>>5).
// Epilogue: per-row max over this half's 128 cols -> max_part[i][j][t][h];
// sum min(s,0)^2 -> one atomicAdd per block.
// ---------------------------------------------------------------------------
__global__ __launch_bounds__(256) void k_gemm(
    const uchar* __restrict__ tn, const uchar* __restrict__ vn,
    float* __restrict__ max_part, float* __restrict__ reg_sum) {
    __shared__ uchar sT[NT * BKB];   // 128 x 128 B = 16 KB
    __shared__ uchar sV[128 * BKB];  // 128 x 128 B = 16 KB
    __shared__ float maxbuf[NT][2];  // row-max partials per wave col-group
    __shared__ float redw[4];

    const int i = blockIdx.x, jj = blockIdx.y;
    const int j = jj >> 1, h = jj & 1;
    const int tid = threadIdx.x;
    const int l = tid & 63, w = tid >> 6;
    const int wr = w >> 1, wc = w & 1;      // wave row-group, col-group
    const int m31 = l & 31, q2 = l >> 5;

    const uchar* tbase = tn + (size_t)i * NT * DD;
    const uchar* vbase = vn + (size_t)jj * 128 * DD;

    // Staging: 16B unit f -> row r = f>>3, phys granule p = f&7 holds
    // logical granule g = (p - r) & 7.  src = r*DD + kk + g*16.
    int t_off[4], v_off[4];
    #pragma unroll
    for (int s = 0; s < 4; ++s) {
        int f = s * 256 + tid;
        int r = f >> 3, p = f & 7, g = (p - r) & 7;
        t_off[s] = r * DD + g * 16;
        v_off[s] = r * DD + g * 16;
    }

    // Fragment read LDS addresses (loop-invariant): lane l, tile row base.
    // k-range of lane: ks*64 + q2*32 .. +32 -> logical granules g0, g0+1.
    int a_ad[2][2][2], b_ad[2][2][2];   // [rt|ct][ks][granule]
    #pragma unroll
    for (int rt = 0; rt < 2; ++rt)
        #pragma unroll
        for (int ks = 0; ks < 2; ++ks) {
            int row = wr * 64 + rt * 32 + m31;
            int g0 = ks * 4 + q2 * 2;
            a_ad[rt][ks][0] = row * BKB + (((g0 + row) & 7) * 16);
            a_ad[rt][ks][1] = row * BKB + (((g0 + 1 + row) & 7) * 16);
            row = wc * 64 + rt * 32 + m31;
            b_ad[rt][ks][0] = row * BKB + (((g0 + row) & 7) * 16);
            b_ad[rt][ks][1] = row * BKB + (((g0 + 1 + row) & 7) * 16);
        }

    f32x16 acc[2][2];
    #pragma unroll
    for (int rt = 0; rt < 2; ++rt)
        #pragma unroll
        for (int ct = 0; ct < 2; ++ct)
            #pragma unroll
            for (int r = 0; r < 16; ++r) acc[rt][ct][r] = 0.0f;

    for (int kk = 0; kk < DD; kk += BKB) {
        #pragma unroll
        for (int s = 0; s < 4; ++s) {
            glds16(tbase + t_off[s] + kk, sT + (s * 256 + tid) * 16);
            glds16(vbase + v_off[s] + kk, sV + (s * 256 + tid) * 16);
        }
        __syncthreads();

        #pragma unroll
        for (int ks = 0; ks < 2; ++ks) {
            i32x8 a[2];
            #pragma unroll
            for (int rt = 0; rt < 2; ++rt) {
                i32x4 lo = *(const i32x4*)(sT + a_ad[rt][ks][0]);
                i32x4 hi = *(const i32x4*)(sT + a_ad[rt][ks][1]);
                a[rt] = (i32x8){lo.x, lo.y, lo.z, lo.w, hi.x, hi.y, hi.z, hi.w};
            }
            #pragma unroll
            for (int ct = 0; ct < 2; ++ct) {
                i32x4 lo = *(const i32x4*)(sV + b_ad[ct][ks][0]);
                i32x4 hi = *(const i32x4*)(sV + b_ad[ct][ks][1]);
                i32x8 b = (i32x8){lo.x, lo.y, lo.z, lo.w, hi.x, hi.y, hi.z, hi.w};
                #pragma unroll
                for (int rt = 0; rt < 2; ++rt)
                    acc[rt][ct] = __builtin_amdgcn_mfma_scale_f32_32x32x64_f8f6f4(
                        a[rt], b, acc[rt][ct],
                        0 /*A fmt=fp8*/, 0 /*B fmt=fp8*/,
                        0, 127 /*scaleA=1.0*/, 0, 127 /*scaleB=1.0*/);
            }
        }
        __syncthreads();
    }

    // Epilogue 1: reg partial = sum of min(s,0)^2 over this lane's 64 values
    float rp = 0.0f;
    #pragma unroll
    for (int rt = 0; rt < 2; ++rt)
        #pragma unroll
        for (int ct = 0; ct < 2; ++ct)
            #pragma unroll
            for (int r = 0; r < 16; ++r) {
                float m = fminf(acc[rt][ct][r], 0.0f);
                rp = fmaf(m, m, rp);
            }

    // Epilogue 2: row max over this half's 128 visual cols.
    #pragma unroll
    for (int rt = 0; rt < 2; ++rt)
        #pragma unroll
        for (int r = 0; r < 16; ++r) {
            float m = fmaxf(acc[rt][0][r], acc[rt][1][r]);
            #pragma unroll
            for (int msk = 1; msk < 32; msk <<= 1)
                m = fmaxf(m, __shfl_xor(m, msk, 64));
            if (m31 == 0)
                maxbuf[wr * 64 + rt * 32 + (r & 3) + 8 * (r >> 2) + 4 * q2][wc] = m;
        }

    #pragma unroll
    for (int off = 32; off; off >>= 1) rp += __shfl_down(rp, off, 64);
    if (l == 0) redw[w] = rp;
    __syncthreads();

    if (tid < NT) {
        float rm = fmaxf(maxbuf[tid][0], maxbuf[tid][1]);
        max_part[(((size_t)i * BB + j) * NT + tid) * 2 + h] = rm;
    }
    if (tid == 0)
        atomicAdd(reg_sum, redw[0] + redw[1] + redw[2] + redw[3]);
}

// ---------------------------------------------------------------------------
// Kernel 3: combine V-halves + masked mean -> clip_sims[i*B+j]
// ---------------------------------------------------------------------------
__global__ __launch_bounds__(NT) void k_clip(
    const float* __restrict__ max_part, const int* __restrict__ mask,
    float* __restrict__ clip_sims) {
    int bx = blockIdx.x;
    int i = bx / BB;
    int t = threadIdx.x;
    float rm = fmaxf(max_part[((size_t)bx * NT + t) * 2],
                     max_part[((size_t)bx * NT + t) * 2 + 1]);
    float mf = (float)mask[i * NT + t];
    float v = rm * mf;
    #pragma unroll
    for (int off = 32; off; off >>= 1) {
        v += __shfl_down(v, off, 64);
        mf += __shfl_down(mf, off, 64);
    }
    __shared__ float a0[2], a1[2];
    int wid = t >> 6;
    if ((t & 63) == 0) { a0[wid] = v; a1[wid] = mf; }
    __syncthreads();
    if (t == 0)
        clip_sims[bx] = (a0[0] + a0[1]) / fmaxf(a1[0] + a1[1], EPSF);
}

// ---------------------------------------------------------------------------
// Kernel 4: final scalar loss. Single block, 256 threads.
// ---------------------------------------------------------------------------
__global__ __launch_bounds__(256) void k_loss(
    const float* __restrict__ clip_sims, const float* __restrict__ reg_sum,
    float* __restrict__ out) {
    __shared__ float sc[BB][BB + 1];
    __shared__ float lrow[BB], lcol[BB];
    int tid = threadIdx.x;
    for (int idx = tid; idx < BB * BB; idx += 256)
        sc[idx / BB][idx % BB] = clip_sims[idx];
    __syncthreads();
    if (tid < BB) {
        int i = tid;
        float m = sc[i][0];
        #pragma unroll
        for (int j = 1; j < BB; ++j) m = fmaxf(m, sc[i][j]);
        float s = 0.0f;
        #pragma unroll
        for (int j = 0; j < BB; ++j) s += expf(sc[i][j] - m);
        lrow[i] = m + logf(s) - sc[i][i];
    } else if (tid < 2 * BB) {
        int i = tid - BB;
        float m = sc[0][i];
        #pragma unroll
        for (int j = 1; j < BB; ++j) m = fmaxf(m, sc[j][i]);
        float s = 0.0f;
        #pragma unroll
        for (int j = 0; j < BB; ++j) s += expf(sc[j][i] - m);
        lcol[i] = m + logf(s) - sc[i][i];
    }
    __syncthreads();
    if (tid == 0) {
        float tot = 0.0f;
        for (int i = 0; i < BB; ++i) tot += lrow[i] + lcol[i];
        float contrastive = tot / (2.0f * BB);
        double denom = (double)BB * BB * NT * NV;  // 134217728
        float reg = 0.15f * (float)((double)reg_sum[0] / denom);
        out[0] = contrastive + reg;
    }
}

// ---------------------------------------------------------------------------
extern "C" void kernel_launch(void* const* d_in, const int* in_sizes, int n_in,
                              void* d_out, int out_size, void* d_ws, size_t ws_size,
                              hipStream_t stream) {
    const float* tf = (const float*)d_in[0];   // (B, NT, D) fp32
    const float* vf = (const float*)d_in[1];   // (B, NV, D) fp32
    const int* mask = (const int*)d_in[2];     // (B, NT) int32
    float* out = (float*)d_out;                // scalar fp32

    char* ws = (char*)d_ws;
    size_t tn_bytes = (size_t)BB * NT * DD;                    // 4 MB fp8
    size_t vn_bytes = (size_t)BB * NV * DD;                    // 8 MB fp8
    size_t mp_bytes = (size_t)BB * BB * NT * 2 * sizeof(float); // 4 MB
    size_t cs_bytes = (size_t)BB * BB * sizeof(float);         // 16 KB

    uchar* tn = (uchar*)ws;
    uchar* vn = (uchar*)(ws + tn_bytes);
    float* max_part = (float*)(ws + tn_bytes + vn_bytes);
    float* clip_sims = (float*)(ws + tn_bytes + vn_bytes + mp_bytes);
    float* reg_sum = (float*)(ws + tn_bytes + vn_bytes + mp_bytes + cs_bytes);

    k_normalize<<<(BB * NT + BB * NV) / 4, 256, 0, stream>>>(tf, vf, tn, vn, reg_sum);
    k_gemm<<<dim3(BB, 2 * BB), 256, 0, stream>>>(tn, vn, max_part, reg_sum);
    k_clip<<<BB * BB, NT, 0, stream>>>(max_part, mask, clip_sims);
    k_loss<<<1, 256, 0, stream>>>(clip_sims, reg_sum, out);
}

// Round 8
// 282.137 us; speedup vs baseline: 1.5411x; 1.5411x over previous
//
#include <hip/hip_runtime.h>
#include <hip/hip_bf16.h>

// Problem constants
#define BB 64     // batch
#define NT 128    // text tokens
#define NV 256    // visual tokens
#define DD 512    // feature dim (bytes per row in fp8)
#define BKB 128   // K-chunk bytes: two 32x32x64 f8f6f4 k-steps
#define EPSF 1e-7f

typedef __attribute__((ext_vector_type(8))) int i32x8;
typedef __attribute__((ext_vector_type(4))) int i32x4;
typedef __attribute__((ext_vector_type(16))) float f32x16;

__device__ __forceinline__ void glds16(const uchar* g, uchar* l) {
    __builtin_amdgcn_global_load_lds(
        (const __attribute__((address_space(1))) unsigned int*)g,
        (__attribute__((address_space(3))) unsigned int*)l, 16, 0, 0);
}

// ---------------------------------------------------------------------------
// Kernel 1: L2-normalize rows, write fp8 e4m3 (OCP). Wave per row; 4 rows
// per 256-thread block. Block 0 zeroes reg_sum.
// ---------------------------------------------------------------------------
__global__ __launch_bounds__(256) void k_normalize(
    const float* __restrict__ tf, const float* __restrict__ vf,
    uchar* __restrict__ tn, uchar* __restrict__ vn,
    float* __restrict__ reg_sum) {
    if (blockIdx.x == 0 && threadIdx.x == 0) *reg_sum = 0.0f;
    const int w = threadIdx.x >> 6, l = threadIdx.x & 63;
    const int row = blockIdx.x * 4 + w;
    const float* src;
    uchar* dst;
    if (row < BB * NT) {
        src = tf + (size_t)row * DD;
        dst = tn + (size_t)row * DD;
    } else {
        int r = row - BB * NT;
        src = vf + (size_t)r * DD;
        dst = vn + (size_t)r * DD;
    }
    float4 x0 = ((const float4*)src)[l * 2];
    float4 x1 = ((const float4*)src)[l * 2 + 1];
    float ss = x0.x * x0.x + x0.y * x0.y + x0.z * x0.z + x0.w * x0.w
             + x1.x * x1.x + x1.y * x1.y + x1.z * x1.z + x1.w * x1.w;
    #pragma unroll
    for (int off = 32; off; off >>= 1) ss += __shfl_xor(ss, off, 64);
    float scale = 1.0f / fmaxf(sqrtf(ss), 1e-12f);
    int p0 = __builtin_amdgcn_cvt_pk_fp8_f32(x0.x * scale, x0.y * scale, 0, 0);
    p0 = __builtin_amdgcn_cvt_pk_fp8_f32(x0.z * scale, x0.w * scale, p0, 1);
    int p1 = __builtin_amdgcn_cvt_pk_fp8_f32(x1.x * scale, x1.y * scale, 0, 0);
    p1 = __builtin_amdgcn_cvt_pk_fp8_f32(x1.z * scale, x1.w * scale, p1, 1);
    ((uint2*)dst)[l] = make_uint2((unsigned)p0, (unsigned)p1);
}

// ---------------------------------------------------------------------------
// Kernel 2 (MX-fp8, 32x32x64): grid (i=64, jj=128); block handles all 128
// text tokens of batch i vs visual tokens [jj*128, jj*128+128) (half of
// batch j = jj>>1). 256 threads = 4 waves (2x2); wave tile 64x64 via 2x2
// tiles of mfma_scale_f32_32x32x64_f8f6f4 (fp8 e4m3, scales=1.0).
// Register ladder (R5-R7 evidence): cap 170 (256,3) -> 96 KB/block acc
// spill, 1.3 GB HBM (R6). Uncapped -> 144 arch VGPRs, unified total >256,
// 1 wave/SIMD, occupancy 11.5%, barrier latency fully exposed (R7).
// Cap 256 via __launch_bounds__(256,2): liveness (~210) fits, no spill,
// AND 2 waves/SIMD guaranteed -> 2 blocks/CU inter-block overlap.
// LDS rows 128 B = 8 16B-granules, rotation swizzle p=(g+row)&7 on the
// DMA global side + frag reads (validated absmax 0.0 for 3 rounds).
// A-frag layout 32x32x64: lane: row = l&31, k = (l>>5)*32 + byte.
// C/D layout 32x32: col = l&31, row = (reg&3) + 8*(reg>>2) + 4*(l>>5).
// Epilogue: per-row max over this half's 128 cols -> max_part[i][j][t][h];
// sum min(s,0)^2 -> one atomicAdd per block.
// ---------------------------------------------------------------------------
__global__ __launch_bounds__(256, 2) void k_gemm(
    const uchar* __restrict__ tn, const uchar* __restrict__ vn,
    float* __restrict__ max_part, float* __restrict__ reg_sum) {
    __shared__ uchar sT[NT * BKB];   // 128 x 128 B = 16 KB
    __shared__ uchar sV[128 * BKB];  // 128 x 128 B = 16 KB
    __shared__ float maxbuf[NT][2];  // row-max partials per wave col-group
    __shared__ float redw[4];

    const int i = blockIdx.x, jj = blockIdx.y;
    const int j = jj >> 1, h = jj & 1;
    const int tid = threadIdx.x;
    const int l = tid & 63, w = tid >> 6;
    const int wr = w >> 1, wc = w & 1;      // wave row-group, col-group
    const int m31 = l & 31, q2 = l >> 5;

    const uchar* tbase = tn + (size_t)i * NT * DD;
    const uchar* vbase = vn + (size_t)jj * 128 * DD;

    // Staging: 16B unit f -> row r = f>>3, phys granule p = f&7 holds
    // logical granule g = (p - r) & 7.  src = r*DD + kk + g*16.
    int t_off[4], v_off[4];
    #pragma unroll
    for (int s = 0; s < 4; ++s) {
        int f = s * 256 + tid;
        int r = f >> 3, p = f & 7, g = (p - r) & 7;
        t_off[s] = r * DD + g * 16;
        v_off[s] = r * DD + g * 16;
    }

    // Fragment read LDS addresses (loop-invariant): lane l, tile row base.
    // k-range of lane: ks*64 + q2*32 .. +32 -> logical granules g0, g0+1.
    int a_ad[2][2][2], b_ad[2][2][2];   // [rt|ct][ks][granule]
    #pragma unroll
    for (int rt = 0; rt < 2; ++rt)
        #pragma unroll
        for (int ks = 0; ks < 2; ++ks) {
            int row = wr * 64 + rt * 32 + m31;
            int g0 = ks * 4 + q2 * 2;
            a_ad[rt][ks][0] = row * BKB + (((g0 + row) & 7) * 16);
            a_ad[rt][ks][1] = row * BKB + (((g0 + 1 + row) & 7) * 16);
            row = wc * 64 + rt * 32 + m31;
            b_ad[rt][ks][0] = row * BKB + (((g0 + row) & 7) * 16);
            b_ad[rt][ks][1] = row * BKB + (((g0 + 1 + row) & 7) * 16);
        }

    f32x16 acc[2][2];
    #pragma unroll
    for (int rt = 0; rt < 2; ++rt)
        #pragma unroll
        for (int ct = 0; ct < 2; ++ct)
            #pragma unroll
            for (int r = 0; r < 16; ++r) acc[rt][ct][r] = 0.0f;

    for (int kk = 0; kk < DD; kk += BKB) {
        #pragma unroll
        for (int s = 0; s < 4; ++s) {
            glds16(tbase + t_off[s] + kk, sT + (s * 256 + tid) * 16);
            glds16(vbase + v_off[s] + kk, sV + (s * 256 + tid) * 16);
        }
        __syncthreads();

        #pragma unroll
        for (int ks = 0; ks < 2; ++ks) {
            i32x8 a[2];
            #pragma unroll
            for (int rt = 0; rt < 2; ++rt) {
                i32x4 lo = *(const i32x4*)(sT + a_ad[rt][ks][0]);
                i32x4 hi = *(const i32x4*)(sT + a_ad[rt][ks][1]);
                a[rt] = (i32x8){lo.x, lo.y, lo.z, lo.w, hi.x, hi.y, hi.z, hi.w};
            }
            #pragma unroll
            for (int ct = 0; ct < 2; ++ct) {
                i32x4 lo = *(const i32x4*)(sV + b_ad[ct][ks][0]);
                i32x4 hi = *(const i32x4*)(sV + b_ad[ct][ks][1]);
                i32x8 b = (i32x8){lo.x, lo.y, lo.z, lo.w, hi.x, hi.y, hi.z, hi.w};
                #pragma unroll
                for (int rt = 0; rt < 2; ++rt)
                    acc[rt][ct] = __builtin_amdgcn_mfma_scale_f32_32x32x64_f8f6f4(
                        a[rt], b, acc[rt][ct],
                        0 /*A fmt=fp8*/, 0 /*B fmt=fp8*/,
                        0, 127 /*scaleA=1.0*/, 0, 127 /*scaleB=1.0*/);
            }
        }
        __syncthreads();
    }

    // Epilogue 1: reg partial = sum of min(s,0)^2 over this lane's 64 values
    float rp = 0.0f;
    #pragma unroll
    for (int rt = 0; rt < 2; ++rt)
        #pragma unroll
        for (int ct = 0; ct < 2; ++ct)
            #pragma unroll
            for (int r = 0; r < 16; ++r) {
                float m = fminf(acc[rt][ct][r], 0.0f);
                rp = fmaf(m, m, rp);
            }

    // Epilogue 2: row max over this half's 128 visual cols.
    #pragma unroll
    for (int rt = 0; rt < 2; ++rt)
        #pragma unroll
        for (int r = 0; r < 16; ++r) {
            float m = fmaxf(acc[rt][0][r], acc[rt][1][r]);
            #pragma unroll
            for (int msk = 1; msk < 32; msk <<= 1)
                m = fmaxf(m, __shfl_xor(m, msk, 64));
            if (m31 == 0)
                maxbuf[wr * 64 + rt * 32 + (r & 3) + 8 * (r >> 2) + 4 * q2][wc] = m;
        }

    #pragma unroll
    for (int off = 32; off; off >>= 1) rp += __shfl_down(rp, off, 64);
    if (l == 0) redw[w] = rp;
    __syncthreads();

    if (tid < NT) {
        float rm = fmaxf(maxbuf[tid][0], maxbuf[tid][1]);
        max_part[(((size_t)i * BB + j) * NT + tid) * 2 + h] = rm;
    }
    if (tid == 0)
        atomicAdd(reg_sum, redw[0] + redw[1] + redw[2] + redw[3]);
}

// ---------------------------------------------------------------------------
// Kernel 3: combine V-halves + masked mean -> clip_sims[i*B+j]
// ---------------------------------------------------------------------------
__global__ __launch_bounds__(NT) void k_clip(
    const float* __restrict__ max_part, const int* __restrict__ mask,
    float* __restrict__ clip_sims) {
    int bx = blockIdx.x;
    int i = bx / BB;
    int t = threadIdx.x;
    float rm = fmaxf(max_part[((size_t)bx * NT + t) * 2],
                     max_part[((size_t)bx * NT + t) * 2 + 1]);
    float mf = (float)mask[i * NT + t];
    float v = rm * mf;
    #pragma unroll
    for (int off = 32; off; off >>= 1) {
        v += __shfl_down(v, off, 64);
        mf += __shfl_down(mf, off, 64);
    }
    __shared__ float a0[2], a1[2];
    int wid = t >> 6;
    if ((t & 63) == 0) { a0[wid] = v; a1[wid] = mf; }
    __syncthreads();
    if (t == 0)
        clip_sims[bx] = (a0[0] + a0[1]) / fmaxf(a1[0] + a1[1], EPSF);
}

// ---------------------------------------------------------------------------
// Kernel 4: final scalar loss. Single block, 256 threads.
// ---------------------------------------------------------------------------
__global__ __launch_bounds__(256) void k_loss(
    const float* __restrict__ clip_sims, const float* __restrict__ reg_sum,
    float* __restrict__ out) {
    __shared__ float sc[BB][BB + 1];
    __shared__ float lrow[BB], lcol[BB];
    int tid = threadIdx.x;
    for (int idx = tid; idx < BB * BB; idx += 256)
        sc[idx / BB][idx % BB] = clip_sims[idx];
    __syncthreads();
    if (tid < BB) {
        int i = tid;
        float m = sc[i][0];
        #pragma unroll
        for (int j = 1; j < BB; ++j) m = fmaxf(m, sc[i][j]);
        float s = 0.0f;
        #pragma unroll
        for (int j = 0; j < BB; ++j) s += expf(sc[i][j] - m);
        lrow[i] = m + logf(s) - sc[i][i];
    } else if (tid < 2 * BB) {
        int i = tid - BB;
        float m = sc[0][i];
        #pragma unroll
        for (int j = 1; j < BB; ++j) m = fmaxf(m, sc[j][i]);
        float s = 0.0f;
        #pragma unroll
        for (int j = 0; j < BB; ++j) s += expf(sc[j][i] - m);
        lcol[i] = m + logf(s) - sc[i][i];
    }
    __syncthreads();
    if (tid == 0) {
        float tot = 0.0f;
        for (int i = 0; i < BB; ++i) tot += lrow[i] + lcol[i];
        float contrastive = tot / (2.0f * BB);
        double denom = (double)BB * BB * NT * NV;  // 134217728
        float reg = 0.15f * (float)((double)reg_sum[0] / denom);
        out[0] = contrastive + reg;
    }
}

// ---------------------------------------------------------------------------
extern "C" void kernel_launch(void* const* d_in, const int* in_sizes, int n_in,
                              void* d_out, int out_size, void* d_ws, size_t ws_size,
                              hipStream_t stream) {
    const float* tf = (const float*)d_in[0];   // (B, NT, D) fp32
    const float* vf = (const float*)d_in[1];   // (B, NV, D) fp32
    const int* mask = (const int*)d_in[2];     // (B, NT) int32
    float* out = (float*)d_out;                // scalar fp32

    char* ws = (char*)d_ws;
    size_t tn_bytes = (size_t)BB * NT * DD;                    // 4 MB fp8
    size_t vn_bytes = (size_t)BB * NV * DD;                    // 8 MB fp8
    size_t mp_bytes = (size_t)BB * BB * NT * 2 * sizeof(float); // 4 MB
    size_t cs_bytes = (size_t)BB * BB * sizeof(float);         // 16 KB

    uchar* tn = (uchar*)ws;
    uchar* vn = (uchar*)(ws + tn_bytes);
    float* max_part = (float*)(ws + tn_bytes + vn_bytes);
    float* clip_sims = (float*)(ws + tn_bytes + vn_bytes + mp_bytes);
    float* reg_sum = (float*)(ws + tn_bytes + vn_bytes + mp_bytes + cs_bytes);

    k_normalize<<<(BB * NT + BB * NV) / 4, 256, 0, stream>>>(tf, vf, tn, vn, reg_sum);
    k_gemm<<<dim3(BB, 2 * BB), 256, 0, stream>>>(tn, vn, max_part, reg_sum);
    k_clip<<<BB * BB, NT, 0, stream>>>(max_part, mask, clip_sims);
    k_loss<<<1, 256, 0, stream>>>(clip_sims, reg_sum, out);
}